// Round 4
// baseline (984.959 us; speedup 1.0000x reference)
//
#include <hip/hip_runtime.h>
#include <stdint.h>

// B=4, T=4096, D=1024, M=1024.  I/O dtype = FLOAT32 (per reference; rounds
// 1-3 misread inputs as bf16 -> NaN from fp32-low-half bit patterns).
// Internals: activations bf16 in ws (fp32 math in-reg, bf16 MFMA);
// xg/L kept fp32 in d_out scratch (dead until final GEMM).  ws ~99MB.

#define R_ROWS 16384
#define DIM    1024
#define MDIM   1024
#define TSEQ   4096
#define NCHUNK 64
#define TCH    64

typedef __attribute__((ext_vector_type(8))) short  bf16x8;
typedef __attribute__((ext_vector_type(8))) ushort u16x8;
typedef __attribute__((ext_vector_type(4))) float  f32x4;

__device__ __forceinline__ float bf2f(ushort u) {
  union { float f; unsigned int i; } x; x.i = ((unsigned int)u) << 16; return x.f;
}
__device__ __forceinline__ ushort f2bf(float f) {
  union { float f; unsigned int i; } x; x.f = f;
  unsigned int r = x.i + 0x7fffu + ((x.i >> 16) & 1u);
  return (ushort)(r >> 16);
}
__device__ __forceinline__ float sigmoidf_(float x) {
  return 1.0f / (1.0f + __expf(-x));
}

// stage 8 fp32 -> 8 bf16 into LDS
__device__ __forceinline__ void stage_w8(const float* g, ushort* lds) {
  const float4 lo = *(const float4*)g;
  const float4 hi = *(const float4*)(g + 4);
  u16x8 v;
  v[0] = f2bf(lo.x); v[1] = f2bf(lo.y); v[2] = f2bf(lo.z); v[3] = f2bf(lo.w);
  v[4] = f2bf(hi.x); v[5] = f2bf(hi.y); v[6] = f2bf(hi.z); v[7] = f2bf(hi.w);
  *(u16x8*)lds = v;
}

// ---------------- RMSNorm: one block per row of 1024 -> bf16 out ------------
template<bool IN_F32>
__global__ __launch_bounds__(256)
void rmsnorm_k(const void* __restrict__ xin, const float* __restrict__ w,
               ushort* __restrict__ y)
{
  __shared__ float red[4];
  const int row = blockIdx.x;
  const int tid = threadIdx.x;
  const size_t base = (size_t)row * DIM + tid * 4;
  float v[4];
  if (IN_F32) {
    const float4 xv = *(const float4*)((const float*)xin + base);
    v[0] = xv.x; v[1] = xv.y; v[2] = xv.z; v[3] = xv.w;
  } else {
    const ushort4 xv = *(const ushort4*)((const ushort*)xin + base);
    v[0] = bf2f(xv.x); v[1] = bf2f(xv.y); v[2] = bf2f(xv.z); v[3] = bf2f(xv.w);
  }
  float ss = v[0]*v[0] + v[1]*v[1] + v[2]*v[2] + v[3]*v[3];
  for (int o = 32; o > 0; o >>= 1) ss += __shfl_down(ss, o, 64);
  const int wave = tid >> 6, lane = tid & 63;
  if (lane == 0) red[wave] = ss;
  __syncthreads();
  const float sum = red[0] + red[1] + red[2] + red[3];
  const float scale = rsqrtf(sum * (1.0f / DIM) + 1e-6f);
  const float4 wv = *(const float4*)(w + tid * 4);
  ushort4 o4;
  o4.x = f2bf(v[0] * scale * wv.x);
  o4.y = f2bf(v[1] * scale * wv.y);
  o4.z = f2bf(v[2] * scale * wv.z);
  o4.w = f2bf(v[3] * scale * wv.w);
  *(ushort4*)(y + base) = o4;
}

// ------------- GEMM C[r,n] = sum_k A[r,k]*W[n,k], K=N=1024 ------------------
// A bf16 (ws), W fp32 (input, cvt to bf16 at staging).  128x128 tile, BK=64.
// MODE 0: out bf16 = sigmoid(v + bias[col])          (bias fp32)
// MODE 1: out bf16 = v + auxf[idx]                    (aux fp32)
// MODE 2: out fp32 = v + bf2f(auxb[idx])              (aux bf16)
template<int MODE>
__global__ __launch_bounds__(256)
void gemm_bt(const ushort* __restrict__ A, const float* __restrict__ W,
             const float* __restrict__ bias, const float* __restrict__ auxf,
             const ushort* __restrict__ auxb, void* __restrict__ out)
{
  __shared__ __align__(16) ushort As[128 * 64];
  __shared__ __align__(16) ushort Bs[128 * 64];
  const int tid = threadIdx.x;
  const int bm = blockIdx.x, bn = blockIdx.y;
  const int wave = tid >> 6, lane = tid & 63;
  const int wm = wave & 1, wn = wave >> 1;
  const int quad = lane >> 4, l16 = lane & 15;

  f32x4 acc[4][4];
#pragma unroll
  for (int i = 0; i < 4; ++i)
#pragma unroll
    for (int j = 0; j < 4; ++j) acc[i][j] = (f32x4){0.f,0.f,0.f,0.f};

  const ushort* Ab = A + (size_t)bm * 128 * 1024;
  const float*  Wb = W + (size_t)bn * 128 * 1024;

  for (int k0 = 0; k0 < 1024; k0 += 64) {
#pragma unroll
    for (int jj = 0; jj < 4; ++jj) {
      const int ci = tid + jj * 256;
      const int row = ci >> 3, c8 = ci & 7;
      const size_t goff = (size_t)row * 1024 + k0 + c8 * 8;
      *(bf16x8*)&As[ci * 8] = *(const bf16x8*)(Ab + goff);
      stage_w8(Wb + goff, &Bs[ci * 8]);
    }
    __syncthreads();
#pragma unroll
    for (int ks = 0; ks < 2; ++ks) {
      bf16x8 a[4], b[4];
      const int ko = ks * 32 + quad * 8;
#pragma unroll
      for (int i = 0; i < 4; ++i)
        a[i] = *(const bf16x8*)&As[(wm * 64 + i * 16 + l16) * 64 + ko];
#pragma unroll
      for (int j = 0; j < 4; ++j)
        b[j] = *(const bf16x8*)&Bs[(wn * 64 + j * 16 + l16) * 64 + ko];
#pragma unroll
      for (int i = 0; i < 4; ++i)
#pragma unroll
        for (int j = 0; j < 4; ++j)
          acc[i][j] = __builtin_amdgcn_mfma_f32_16x16x32_bf16(
              a[i], b[j], acc[i][j], 0, 0, 0);
    }
    __syncthreads();
  }

  const int rbase = bm * 128 + wm * 64 + quad * 4;
  const int cbase = bn * 128 + wn * 64 + l16;
#pragma unroll
  for (int j = 0; j < 4; ++j) {
    const int col = cbase + j * 16;
    const float bv = (MODE == 0) ? bias[col] : 0.f;
#pragma unroll
    for (int i = 0; i < 4; ++i) {
#pragma unroll
      for (int g = 0; g < 4; ++g) {
        const size_t idx = (size_t)(rbase + i * 16 + g) * 1024 + col;
        const float v = acc[i][j][g];
        if (MODE == 0)      ((ushort*)out)[idx] = f2bf(sigmoidf_(v + bv));
        else if (MODE == 1) ((ushort*)out)[idx] = f2bf(v + auxf[idx]);
        else                ((float*)out)[idx]  = v + bf2f(auxb[idx]);
      }
    }
  }
}

// --------- Gated GEMM: out = (A·W1^T) * sigmoid(A·W2^T + b2) ----------------
// A bf16, W1/W2 fp32->bf16 staging.  OUTF: fp32 (xg) or bf16 (ff).
template<bool OUTF>
__global__ __launch_bounds__(256)
void gemm_gated(const ushort* __restrict__ A, const float* __restrict__ W1,
                const float* __restrict__ W2, const float* __restrict__ b2,
                void* __restrict__ out)
{
  __shared__ __align__(16) ushort As[128 * 64];
  __shared__ __align__(16) ushort B1s[128 * 64];
  __shared__ __align__(16) ushort B2s[128 * 64];
  const int tid = threadIdx.x;
  const int bm = blockIdx.x, bn = blockIdx.y;
  const int wave = tid >> 6, lane = tid & 63;
  const int wm = wave & 1, wn = wave >> 1;
  const int quad = lane >> 4, l16 = lane & 15;

  f32x4 acc1[4][4], acc2[4][4];
#pragma unroll
  for (int i = 0; i < 4; ++i)
#pragma unroll
    for (int j = 0; j < 4; ++j) {
      acc1[i][j] = (f32x4){0.f,0.f,0.f,0.f};
      acc2[i][j] = (f32x4){0.f,0.f,0.f,0.f};
    }

  const ushort* Ab  = A  + (size_t)bm * 128 * 1024;
  const float*  W1b = W1 + (size_t)bn * 128 * 1024;
  const float*  W2b = W2 + (size_t)bn * 128 * 1024;

  for (int k0 = 0; k0 < 1024; k0 += 64) {
#pragma unroll
    for (int jj = 0; jj < 4; ++jj) {
      const int ci = tid + jj * 256;
      const int row = ci >> 3, c8 = ci & 7;
      const size_t goff = (size_t)row * 1024 + k0 + c8 * 8;
      *(bf16x8*)&As[ci * 8] = *(const bf16x8*)(Ab + goff);
      stage_w8(W1b + goff, &B1s[ci * 8]);
      stage_w8(W2b + goff, &B2s[ci * 8]);
    }
    __syncthreads();
#pragma unroll
    for (int ks = 0; ks < 2; ++ks) {
      bf16x8 a[4], b1[4], b2v[4];
      const int ko = ks * 32 + quad * 8;
#pragma unroll
      for (int i = 0; i < 4; ++i)
        a[i] = *(const bf16x8*)&As[(wm * 64 + i * 16 + l16) * 64 + ko];
#pragma unroll
      for (int j = 0; j < 4; ++j) {
        b1[j]  = *(const bf16x8*)&B1s[(wn * 64 + j * 16 + l16) * 64 + ko];
        b2v[j] = *(const bf16x8*)&B2s[(wn * 64 + j * 16 + l16) * 64 + ko];
      }
#pragma unroll
      for (int i = 0; i < 4; ++i)
#pragma unroll
        for (int j = 0; j < 4; ++j) {
          acc1[i][j] = __builtin_amdgcn_mfma_f32_16x16x32_bf16(
              a[i], b1[j], acc1[i][j], 0, 0, 0);
          acc2[i][j] = __builtin_amdgcn_mfma_f32_16x16x32_bf16(
              a[i], b2v[j], acc2[i][j], 0, 0, 0);
        }
    }
    __syncthreads();
  }

  const int rbase = bm * 128 + wm * 64 + quad * 4;
  const int cbase = bn * 128 + wn * 64 + l16;
#pragma unroll
  for (int j = 0; j < 4; ++j) {
    const int col = cbase + j * 16;
    const float bv = b2[col];
#pragma unroll
    for (int i = 0; i < 4; ++i) {
#pragma unroll
      for (int g = 0; g < 4; ++g) {
        const size_t idx = (size_t)(rbase + i * 16 + g) * 1024 + col;
        const float v = acc1[i][j][g] * sigmoidf_(acc2[i][j][g] + bv);
        if (OUTF) ((float*)out)[idx] = v;
        else      ((ushort*)out)[idx] = f2bf(v);
      }
    }
  }
}

// ------------- linear recurrence h_t = xg_t + r_t*h_{t-1}, chunked ----------
__global__ __launch_bounds__(256)
void linrec_passA(float* __restrict__ xg, const ushort* __restrict__ r,
                  float* __restrict__ cL, float* __restrict__ cP)
{
  const int g = blockIdx.x * 256 + threadIdx.x;   // [0, 262144)
  const int m = g & (MDIM - 1);
  const int bc = g >> 10;
  const int b = bc >> 6, c = bc & 63;
  const size_t base = ((size_t)(b * TSEQ + c * TCH)) * MDIM + m;
  float h = 0.f, p = 1.f;
  for (int t = 0; t < TCH; ++t) {
    const size_t idx = base + (size_t)t * MDIM;
    const float xv = xg[idx], rv = bf2f(r[idx]);
    h = fmaf(rv, h, xv);
    p *= rv;
    xg[idx] = h;       // local prefix (chunk-start state 0), in place, fp32
  }
  cL[c * 4096 + b * MDIM + m] = h;
  cP[c * 4096 + b * MDIM + m] = p;
}

__global__ __launch_bounds__(256)
void linrec_passB(const float* __restrict__ cL, const float* __restrict__ cP,
                  const float* __restrict__ mem, float* __restrict__ cIn,
                  float* __restrict__ memout)
{
  const int g = blockIdx.x * 256 + threadIdx.x;   // [0,4096)
  float carry = mem[g];
  for (int c = 0; c < NCHUNK; ++c) {
    cIn[c * 4096 + g] = carry;
    carry = fmaf(cP[c * 4096 + g], carry, cL[c * 4096 + g]);
  }
  memout[g] = carry;
}

__global__ __launch_bounds__(256)
void linrec_passC(const float* __restrict__ L, const ushort* __restrict__ r,
                  const ushort* __restrict__ og, const float* __restrict__ cIn,
                  ushort* __restrict__ s)
{
  const int g = blockIdx.x * 256 + threadIdx.x;
  const int m = g & (MDIM - 1);
  const int bc = g >> 10;
  const int b = bc >> 6, c = bc & 63;
  const size_t base = ((size_t)(b * TSEQ + c * TCH)) * MDIM + m;
  const float cin = cIn[c * 4096 + b * MDIM + m];
  float p = 1.f;
  for (int t = 0; t < TCH; ++t) {
    const size_t idx = base + (size_t)t * MDIM;
    p *= bf2f(r[idx]);
    float h = fmaf(p, cin, L[idx]);
    h = fminf(fmaxf(h, -1e4f), 1e4f);   // insurance; inert when correct
    const float sv = h / (1.0f + fabsf(h)) * bf2f(og[idx]);
    s[idx] = f2bf(sv);
  }
}

// ---------------- launch ----------------
extern "C" void kernel_launch(void* const* d_in, const int* in_sizes, int n_in,
                              void* d_out, int out_size, void* d_ws, size_t ws_size,
                              hipStream_t stream)
{
  const float* x        = (const float*)d_in[0];
  const float* mem      = (const float*)d_in[1];
  const float* norm_w   = (const float*)d_in[2];
  const float* wr_w     = (const float*)d_in[3];
  const float* wr_b     = (const float*)d_in[4];
  const float* wi_w     = (const float*)d_in[5];
  const float* wig_w    = (const float*)d_in[6];
  const float* wig_b    = (const float*)d_in[7];
  const float* wog_w    = (const float*)d_in[8];
  const float* wog_b    = (const float*)d_in[9];
  const float* wo_w     = (const float*)d_in[10];
  const float* ffnorm_w = (const float*)d_in[11];
  const float* ffn_wi_w = (const float*)d_in[12];
  const float* ffn_wg_w = (const float*)d_in[13];
  const float* ffn_wg_b = (const float*)d_in[14];
  const float* ffn_wo_w = (const float*)d_in[15];
  float* outF = (float*)d_out;                 // 16777216 x + 4096 mem_out

  // ws layout (~99MB), identical footprint to rounds 2-3 (known to run):
  char* ws = (char*)d_ws;
  ushort* y   = (ushort*)(ws);                 // 32MB bf16: y -> s -> ff
  ushort* r   = (ushort*)(ws + 33554432ULL);   // 32MB bf16: r -> z
  ushort* og  = (ushort*)(ws + 67108864ULL);   // 32MB bf16: og -> x1
  float*  cL  = (float*) (ws + 100663296ULL);  // 1MB
  float*  cP  = (float*) (ws + 101711872ULL);  // 1MB
  float*  cIn = (float*) (ws + 102760448ULL);  // 1MB
  float*  xgL = outF;                          // d_out[0..16M floats) scratch
  ushort* s   = y;
  ushort* x1  = og;
  ushort* z   = r;
  ushort* ff  = y;

  const dim3 gg(128, 8);

  // sqrll branch
  rmsnorm_k<true><<<R_ROWS, 256, 0, stream>>>(x, norm_w, y);
  gemm_bt<0><<<gg, 256, 0, stream>>>(y, wr_w,  wr_b,  nullptr, nullptr, r);
  gemm_bt<0><<<gg, 256, 0, stream>>>(y, wog_w, wog_b, nullptr, nullptr, og);
  gemm_gated<true><<<gg, 256, 0, stream>>>(y, wi_w, wig_w, wig_b, xgL);
  linrec_passA<<<1024, 256, 0, stream>>>(xgL, r, cL, cP);
  linrec_passB<<<16, 256, 0, stream>>>(cL, cP, mem, cIn, outF + 16777216);
  linrec_passC<<<1024, 256, 0, stream>>>(xgL, r, og, cIn, s);
  gemm_bt<1><<<gg, 256, 0, stream>>>(s, wo_w, nullptr, x, nullptr, x1);
  // ffn branch
  rmsnorm_k<false><<<R_ROWS, 256, 0, stream>>>(x1, ffnorm_w, z);
  gemm_gated<false><<<gg, 256, 0, stream>>>(z, ffn_wi_w, ffn_wg_w, ffn_wg_b, ff);
  gemm_bt<2><<<gg, 256, 0, stream>>>(ff, ffn_wo_w, nullptr, nullptr, x1, outF);
}

// Round 5
// 766.418 us; speedup vs baseline: 1.2851x; 1.2851x over previous
//
#include <hip/hip_runtime.h>
#include <stdint.h>

// B=4, T=4096, D=1024, M=1024.  I/O fp32.  Round 5: pre-convert 7 weight
// matrices to bf16 (stored in d_out[32..46MB), dead until final GEMM), all
// main GEMMs pure-bf16 with 16B global_load_lds staging (m97 structure).
// xg/L stored bf16 in d_out[0..32MB).  Final GEMM (ffn_wo) keeps fp32
// cvt-staging since its output overwrites the weight scratch.

#define R_ROWS 16384
#define DIM    1024
#define MDIM   1024
#define TSEQ   4096
#define NCHUNK 64
#define TCH    64

typedef __attribute__((ext_vector_type(8))) short  bf16x8;
typedef __attribute__((ext_vector_type(8))) ushort u16x8;
typedef __attribute__((ext_vector_type(4))) float  f32x4;

__device__ __forceinline__ float bf2f(ushort u) {
  union { float f; unsigned int i; } x; x.i = ((unsigned int)u) << 16; return x.f;
}
__device__ __forceinline__ ushort f2bf(float f) {
  union { float f; unsigned int i; } x; x.f = f;
  unsigned int r = x.i + 0x7fffu + ((x.i >> 16) & 1u);
  return (ushort)(r >> 16);
}
__device__ __forceinline__ float sigmoidf_(float x) {
  return 1.0f / (1.0f + __expf(-x));
}
__device__ __forceinline__ void load_lds16(const void* g, void* s) {
  __builtin_amdgcn_global_load_lds(
      (const __attribute__((address_space(1))) void*)g,
      (__attribute__((address_space(3))) void*)s, 16, 0, 0);
}
// stage 8 fp32 -> 8 bf16 into LDS (final GEMM only)
__device__ __forceinline__ void stage_w8(const float* g, ushort* lds) {
  const float4 lo = *(const float4*)g;
  const float4 hi = *(const float4*)(g + 4);
  u16x8 v;
  v[0] = f2bf(lo.x); v[1] = f2bf(lo.y); v[2] = f2bf(lo.z); v[3] = f2bf(lo.w);
  v[4] = f2bf(hi.x); v[5] = f2bf(hi.y); v[6] = f2bf(hi.z); v[7] = f2bf(hi.w);
  *(u16x8*)lds = v;
}

// ------------- weight pre-convert: 7 matrices of 1M fp32 -> bf16 ------------
__global__ __launch_bounds__(256)
void cvt_weights(const float* __restrict__ w0, const float* __restrict__ w1,
                 const float* __restrict__ w2, const float* __restrict__ w3,
                 const float* __restrict__ w4, const float* __restrict__ w5,
                 const float* __restrict__ w6, ushort* __restrict__ dst)
{
  const float* src;
  switch (blockIdx.y) {
    case 0: src = w0; break; case 1: src = w1; break;
    case 2: src = w2; break; case 3: src = w3; break;
    case 4: src = w4; break; case 5: src = w5; break;
    default: src = w6; break;
  }
  const int i = blockIdx.x * 256 + threadIdx.x;           // [0, 262144)
  const size_t off = (size_t)blockIdx.y * 1048576 + (size_t)i * 4;
  const float4 v = *(const float4*)(src + (size_t)i * 4);
  ushort4 o; o.x = f2bf(v.x); o.y = f2bf(v.y); o.z = f2bf(v.z); o.w = f2bf(v.w);
  *(ushort4*)(dst + off) = o;
}

// ---------------- RMSNorm: one block per row of 1024 -> bf16 out ------------
template<bool IN_F32>
__global__ __launch_bounds__(256)
void rmsnorm_k(const void* __restrict__ xin, const float* __restrict__ w,
               ushort* __restrict__ y)
{
  __shared__ float red[4];
  const int row = blockIdx.x;
  const int tid = threadIdx.x;
  const size_t base = (size_t)row * DIM + tid * 4;
  float v[4];
  if (IN_F32) {
    const float4 xv = *(const float4*)((const float*)xin + base);
    v[0] = xv.x; v[1] = xv.y; v[2] = xv.z; v[3] = xv.w;
  } else {
    const ushort4 xv = *(const ushort4*)((const ushort*)xin + base);
    v[0] = bf2f(xv.x); v[1] = bf2f(xv.y); v[2] = bf2f(xv.z); v[3] = bf2f(xv.w);
  }
  float ss = v[0]*v[0] + v[1]*v[1] + v[2]*v[2] + v[3]*v[3];
  for (int o = 32; o > 0; o >>= 1) ss += __shfl_down(ss, o, 64);
  const int wave = tid >> 6, lane = tid & 63;
  if (lane == 0) red[wave] = ss;
  __syncthreads();
  const float sum = red[0] + red[1] + red[2] + red[3];
  const float scale = rsqrtf(sum * (1.0f / DIM) + 1e-6f);
  const float4 wv = *(const float4*)(w + tid * 4);
  ushort4 o4;
  o4.x = f2bf(v[0] * scale * wv.x);
  o4.y = f2bf(v[1] * scale * wv.y);
  o4.z = f2bf(v[2] * scale * wv.z);
  o4.w = f2bf(v[3] * scale * wv.w);
  *(ushort4*)(y + base) = o4;
}

// ---- all-bf16 GEMM, global_load_lds staging.  C[r,n]=sum_k A[r,k]W[n,k] ----
// MODE 0: out bf16 = sigmoid(v + bias[col]);  MODE 1: out bf16 = v + auxf[idx]
template<int MODE>
__global__ __launch_bounds__(256)
void gemm_bb(const ushort* __restrict__ A, const ushort* __restrict__ W,
             const float* __restrict__ bias, const float* __restrict__ auxf,
             ushort* __restrict__ out)
{
  __shared__ __align__(16) ushort As[128 * 64];
  __shared__ __align__(16) ushort Bs[128 * 64];
  const int tid = threadIdx.x;
  const int bm = blockIdx.x, bn = blockIdx.y;
  const int wave = tid >> 6, lane = tid & 63;
  const int wm = wave & 1, wn = wave >> 1;
  const int quad = lane >> 4, l16 = lane & 15;

  f32x4 acc[4][4];
#pragma unroll
  for (int i = 0; i < 4; ++i)
#pragma unroll
    for (int j = 0; j < 4; ++j) acc[i][j] = (f32x4){0.f,0.f,0.f,0.f};

  const ushort* Ab = A + (size_t)bm * 128 * 1024;
  const ushort* Wb = W + (size_t)bn * 128 * 1024;

  for (int k0 = 0; k0 < 1024; k0 += 64) {
#pragma unroll
    for (int jj = 0; jj < 4; ++jj) {
      const int ci = tid + jj * 256;
      const int row = ci >> 3, c8 = ci & 7;
      const size_t goff = (size_t)row * 1024 + k0 + c8 * 8;
      load_lds16(Ab + goff, &As[ci * 8]);
      load_lds16(Wb + goff, &Bs[ci * 8]);
    }
    __syncthreads();
#pragma unroll
    for (int ks = 0; ks < 2; ++ks) {
      bf16x8 a[4], b[4];
      const int ko = ks * 32 + quad * 8;
#pragma unroll
      for (int i = 0; i < 4; ++i)
        a[i] = *(const bf16x8*)&As[(wm * 64 + i * 16 + l16) * 64 + ko];
#pragma unroll
      for (int j = 0; j < 4; ++j)
        b[j] = *(const bf16x8*)&Bs[(wn * 64 + j * 16 + l16) * 64 + ko];
#pragma unroll
      for (int i = 0; i < 4; ++i)
#pragma unroll
        for (int j = 0; j < 4; ++j)
          acc[i][j] = __builtin_amdgcn_mfma_f32_16x16x32_bf16(
              a[i], b[j], acc[i][j], 0, 0, 0);
    }
    __syncthreads();
  }

  const int rbase = bm * 128 + wm * 64 + quad * 4;
  const int cbase = bn * 128 + wn * 64 + l16;
#pragma unroll
  for (int j = 0; j < 4; ++j) {
    const int col = cbase + j * 16;
    const float bv = (MODE == 0) ? bias[col] : 0.f;
#pragma unroll
    for (int i = 0; i < 4; ++i) {
#pragma unroll
      for (int g = 0; g < 4; ++g) {
        const size_t idx = (size_t)(rbase + i * 16 + g) * 1024 + col;
        const float v = acc[i][j][g];
        out[idx] = (MODE == 0) ? f2bf(sigmoidf_(v + bv))
                               : f2bf(v + auxf[idx]);
      }
    }
  }
}

// --- gated all-bf16: out bf16 = (A·W1^T) * sigmoid(A·W2^T + b2), glds -------
__global__ __launch_bounds__(256)
void gated_bb(const ushort* __restrict__ A, const ushort* __restrict__ W1,
              const ushort* __restrict__ W2, const float* __restrict__ b2,
              ushort* __restrict__ out)
{
  __shared__ __align__(16) ushort As[128 * 64];
  __shared__ __align__(16) ushort B1s[128 * 64];
  __shared__ __align__(16) ushort B2s[128 * 64];
  const int tid = threadIdx.x;
  const int bm = blockIdx.x, bn = blockIdx.y;
  const int wave = tid >> 6, lane = tid & 63;
  const int wm = wave & 1, wn = wave >> 1;
  const int quad = lane >> 4, l16 = lane & 15;

  f32x4 acc1[4][4], acc2[4][4];
#pragma unroll
  for (int i = 0; i < 4; ++i)
#pragma unroll
    for (int j = 0; j < 4; ++j) {
      acc1[i][j] = (f32x4){0.f,0.f,0.f,0.f};
      acc2[i][j] = (f32x4){0.f,0.f,0.f,0.f};
    }

  const ushort* Ab  = A  + (size_t)bm * 128 * 1024;
  const ushort* W1b = W1 + (size_t)bn * 128 * 1024;
  const ushort* W2b = W2 + (size_t)bn * 128 * 1024;

  for (int k0 = 0; k0 < 1024; k0 += 64) {
#pragma unroll
    for (int jj = 0; jj < 4; ++jj) {
      const int ci = tid + jj * 256;
      const int row = ci >> 3, c8 = ci & 7;
      const size_t goff = (size_t)row * 1024 + k0 + c8 * 8;
      load_lds16(Ab  + goff, &As[ci * 8]);
      load_lds16(W1b + goff, &B1s[ci * 8]);
      load_lds16(W2b + goff, &B2s[ci * 8]);
    }
    __syncthreads();
#pragma unroll
    for (int ks = 0; ks < 2; ++ks) {
      bf16x8 a[4], b1[4], b2v[4];
      const int ko = ks * 32 + quad * 8;
#pragma unroll
      for (int i = 0; i < 4; ++i)
        a[i] = *(const bf16x8*)&As[(wm * 64 + i * 16 + l16) * 64 + ko];
#pragma unroll
      for (int j = 0; j < 4; ++j) {
        b1[j]  = *(const bf16x8*)&B1s[(wn * 64 + j * 16 + l16) * 64 + ko];
        b2v[j] = *(const bf16x8*)&B2s[(wn * 64 + j * 16 + l16) * 64 + ko];
      }
#pragma unroll
      for (int i = 0; i < 4; ++i)
#pragma unroll
        for (int j = 0; j < 4; ++j) {
          acc1[i][j] = __builtin_amdgcn_mfma_f32_16x16x32_bf16(
              a[i], b1[j], acc1[i][j], 0, 0, 0);
          acc2[i][j] = __builtin_amdgcn_mfma_f32_16x16x32_bf16(
              a[i], b2v[j], acc2[i][j], 0, 0, 0);
        }
    }
    __syncthreads();
  }

  const int rbase = bm * 128 + wm * 64 + quad * 4;
  const int cbase = bn * 128 + wn * 64 + l16;
#pragma unroll
  for (int j = 0; j < 4; ++j) {
    const int col = cbase + j * 16;
    const float bv = b2[col];
#pragma unroll
    for (int i = 0; i < 4; ++i) {
#pragma unroll
      for (int g = 0; g < 4; ++g) {
        const size_t idx = (size_t)(rbase + i * 16 + g) * 1024 + col;
        out[idx] = f2bf(acc1[i][j][g] * sigmoidf_(acc2[i][j][g] + bv));
      }
    }
  }
}

// ---- final GEMM: A bf16 glds, W fp32 cvt-staged, out fp32 = v + bf2f(aux) --
__global__ __launch_bounds__(256)
void gemm_final(const ushort* __restrict__ A, const float* __restrict__ W,
                const ushort* __restrict__ auxb, float* __restrict__ out)
{
  __shared__ __align__(16) ushort As[128 * 64];
  __shared__ __align__(16) ushort Bs[128 * 64];
  const int tid = threadIdx.x;
  const int bm = blockIdx.x, bn = blockIdx.y;
  const int wave = tid >> 6, lane = tid & 63;
  const int wm = wave & 1, wn = wave >> 1;
  const int quad = lane >> 4, l16 = lane & 15;

  f32x4 acc[4][4];
#pragma unroll
  for (int i = 0; i < 4; ++i)
#pragma unroll
    for (int j = 0; j < 4; ++j) acc[i][j] = (f32x4){0.f,0.f,0.f,0.f};

  const ushort* Ab = A + (size_t)bm * 128 * 1024;
  const float*  Wb = W + (size_t)bn * 128 * 1024;

  for (int k0 = 0; k0 < 1024; k0 += 64) {
#pragma unroll
    for (int jj = 0; jj < 4; ++jj) {
      const int ci = tid + jj * 256;
      const int row = ci >> 3, c8 = ci & 7;
      const size_t goff = (size_t)row * 1024 + k0 + c8 * 8;
      load_lds16(Ab + goff, &As[ci * 8]);
      stage_w8(Wb + goff, &Bs[ci * 8]);
    }
    __syncthreads();
#pragma unroll
    for (int ks = 0; ks < 2; ++ks) {
      bf16x8 a[4], b[4];
      const int ko = ks * 32 + quad * 8;
#pragma unroll
      for (int i = 0; i < 4; ++i)
        a[i] = *(const bf16x8*)&As[(wm * 64 + i * 16 + l16) * 64 + ko];
#pragma unroll
      for (int j = 0; j < 4; ++j)
        b[j] = *(const bf16x8*)&Bs[(wn * 64 + j * 16 + l16) * 64 + ko];
#pragma unroll
      for (int i = 0; i < 4; ++i)
#pragma unroll
        for (int j = 0; j < 4; ++j)
          acc[i][j] = __builtin_amdgcn_mfma_f32_16x16x32_bf16(
              a[i], b[j], acc[i][j], 0, 0, 0);
    }
    __syncthreads();
  }

  const int rbase = bm * 128 + wm * 64 + quad * 4;
  const int cbase = bn * 128 + wn * 64 + l16;
#pragma unroll
  for (int j = 0; j < 4; ++j) {
    const int col = cbase + j * 16;
#pragma unroll
    for (int i = 0; i < 4; ++i) {
#pragma unroll
      for (int g = 0; g < 4; ++g) {
        const size_t idx = (size_t)(rbase + i * 16 + g) * 1024 + col;
        out[idx] = acc[i][j][g] + bf2f(auxb[idx]);
      }
    }
  }
}

// ------------- linear recurrence h_t = xg_t + r_t*h_{t-1}, chunked ----------
__global__ __launch_bounds__(256)
void linrec_passA(ushort* __restrict__ xg, const ushort* __restrict__ r,
                  float* __restrict__ cL, float* __restrict__ cP)
{
  const int g = blockIdx.x * 256 + threadIdx.x;   // [0, 262144)
  const int m = g & (MDIM - 1);
  const int bc = g >> 10;
  const int b = bc >> 6, c = bc & 63;
  const size_t base = ((size_t)(b * TSEQ + c * TCH)) * MDIM + m;
  float h = 0.f, p = 1.f;
  for (int t = 0; t < TCH; ++t) {
    const size_t idx = base + (size_t)t * MDIM;
    const float xv = bf2f(xg[idx]), rv = bf2f(r[idx]);
    h = fmaf(rv, h, xv);
    p *= rv;
    xg[idx] = f2bf(h);       // local prefix (chunk-start state 0), in place
  }
  cL[c * 4096 + b * MDIM + m] = h;
  cP[c * 4096 + b * MDIM + m] = p;
}

__global__ __launch_bounds__(256)
void linrec_passB(const float* __restrict__ cL, const float* __restrict__ cP,
                  const float* __restrict__ mem, float* __restrict__ cIn,
                  float* __restrict__ memout)
{
  const int g = blockIdx.x * 256 + threadIdx.x;   // [0,4096)
  float carry = mem[g];
  for (int c = 0; c < NCHUNK; ++c) {
    cIn[c * 4096 + g] = carry;
    carry = fmaf(cP[c * 4096 + g], carry, cL[c * 4096 + g]);
  }
  memout[g] = carry;
}

__global__ __launch_bounds__(256)
void linrec_passC(const ushort* __restrict__ L, const ushort* __restrict__ r,
                  const ushort* __restrict__ og, const float* __restrict__ cIn,
                  ushort* __restrict__ s)
{
  const int g = blockIdx.x * 256 + threadIdx.x;
  const int m = g & (MDIM - 1);
  const int bc = g >> 10;
  const int b = bc >> 6, c = bc & 63;
  const size_t base = ((size_t)(b * TSEQ + c * TCH)) * MDIM + m;
  const float cin = cIn[c * 4096 + b * MDIM + m];
  float p = 1.f;
  for (int t = 0; t < TCH; ++t) {
    const size_t idx = base + (size_t)t * MDIM;
    p *= bf2f(r[idx]);
    const float h = fmaf(p, cin, bf2f(L[idx]));
    const float sv = h / (1.0f + fabsf(h)) * bf2f(og[idx]);
    s[idx] = f2bf(sv);
  }
}

// ---------------- launch ----------------
extern "C" void kernel_launch(void* const* d_in, const int* in_sizes, int n_in,
                              void* d_out, int out_size, void* d_ws, size_t ws_size,
                              hipStream_t stream)
{
  const float* x        = (const float*)d_in[0];
  const float* mem      = (const float*)d_in[1];
  const float* norm_w   = (const float*)d_in[2];
  const float* wr_w     = (const float*)d_in[3];
  const float* wr_b     = (const float*)d_in[4];
  const float* wi_w     = (const float*)d_in[5];
  const float* wig_w    = (const float*)d_in[6];
  const float* wig_b    = (const float*)d_in[7];
  const float* wog_w    = (const float*)d_in[8];
  const float* wog_b    = (const float*)d_in[9];
  const float* wo_w     = (const float*)d_in[10];
  const float* ffnorm_w = (const float*)d_in[11];
  const float* ffn_wi_w = (const float*)d_in[12];
  const float* ffn_wg_w = (const float*)d_in[13];
  const float* ffn_wg_b = (const float*)d_in[14];
  const float* ffn_wo_w = (const float*)d_in[15];
  float* outF = (float*)d_out;

  // d_out scratch (dead until final GEMM / passB):
  ushort* xgL  = (ushort*)d_out;                        // [0,32MB): xg/L bf16
  ushort* wbf  = (ushort*)((char*)d_out + 33554432ULL); // [32,46MB): 7x bf16 W
  float*  memoutF = outF + 16777216;                    // mem_out fp32

  // ws (~104MB, same footprint as round 4):
  char* ws = (char*)d_ws;
  ushort* y   = (ushort*)(ws);                 // 32MB bf16: y -> s -> ff
  ushort* r   = (ushort*)(ws + 33554432ULL);   // 32MB bf16: r -> z
  ushort* og  = (ushort*)(ws + 67108864ULL);   // 32MB bf16: og -> x1
  float*  cL  = (float*) (ws + 100663296ULL);  // 1MB
  float*  cP  = (float*) (ws + 101711872ULL);  // 1MB
  float*  cIn = (float*) (ws + 102760448ULL);  // 1MB
  ushort* s   = y;
  ushort* x1  = og;
  ushort* z   = r;
  ushort* ff  = y;

  // bf16 weight slots (1M elems each): 0=wr 1=wog 2=wi 3=wig 4=wo 5=ffn_wi 6=ffn_wg
  ushort* wr_bf   = wbf + 0 * 1048576;
  ushort* wog_bf  = wbf + 1 * 1048576;
  ushort* wi_bf   = wbf + 2 * 1048576;
  ushort* wig_bf  = wbf + 3 * 1048576;
  ushort* wo_bf   = wbf + 4 * 1048576;
  ushort* fwi_bf  = wbf + 5 * 1048576;
  ushort* fwg_bf  = wbf + 6 * 1048576;

  const dim3 gg(128, 8);

  cvt_weights<<<dim3(1024, 7), 256, 0, stream>>>(
      wr_w, wog_w, wi_w, wig_w, wo_w, ffn_wi_w, ffn_wg_w, wbf);

  // sqrll branch
  rmsnorm_k<true><<<R_ROWS, 256, 0, stream>>>(x, norm_w, y);
  gemm_bb<0><<<gg, 256, 0, stream>>>(y, wr_bf,  wr_b,  nullptr, r);
  gemm_bb<0><<<gg, 256, 0, stream>>>(y, wog_bf, wog_b, nullptr, og);
  gated_bb<<<gg, 256, 0, stream>>>(y, wi_bf, wig_bf, wig_b, xgL);
  linrec_passA<<<1024, 256, 0, stream>>>(xgL, r, cL, cP);
  linrec_passB<<<16, 256, 0, stream>>>(cL, cP, mem, cIn, memoutF);
  linrec_passC<<<1024, 256, 0, stream>>>(xgL, r, og, cIn, s);
  gemm_bb<1><<<gg, 256, 0, stream>>>(s, wo_bf, nullptr, x, x1);
  // ffn branch
  rmsnorm_k<false><<<R_ROWS, 256, 0, stream>>>(x1, ffnorm_w, z);
  gated_bb<<<gg, 256, 0, stream>>>(z, fwi_bf, fwg_bf, ffn_wg_b, ff);
  gemm_final<<<gg, 256, 0, stream>>>(ff, ffn_wo_w, x1, outF);
}